// Round 7
// baseline (166.146 us; speedup 1.0000x reference)
//
#include <hip/hip_runtime.h>
#include <math.h>

// ---------------------------------------------------------------------------
// TwoDimEquivalent: B=8192 independent nonlinear scans of length T=2048.
//  * gauss_int depends only on s = delta^2 -> float2 pair-LUT in LDS
//    (one ds_read_b64 per step; LUT = exact 64-pt GL sum, nodes via Newton).
//  * contraction ~0.92/step -> 32 chunks x 64 steps, <=128-step warmup.
//  * u: coalesced float4 -> double-buffered LDS tile, ONE barrier per 8-step
//    group (2-buffer rotation makes the second barrier unnecessary).
//  * z: 64 values/thread in registers, terminal flush via 32x65 LDS transpose
//    tile (aliases u buffers) -> per-wave 256 B contiguous row segments.
// History: R1 grid bug; R2 90us (WRITE 161MB partial-line amplification);
// R4 NT-loads bypass LLC, regressed; R5 58us (WRITE fixed 74MB, Occ 15%,
// latency-bound); R6 crash: c=1 had t_begin = 64-128 = -64 -> OOB read.
// R7: clamp t_begin to 0 (chunk 1 then starts from the EXACT zero init).
// ---------------------------------------------------------------------------

#define Bsz   8192
#define Tlen  2048
#define TP1   2049
#define NQ    64
#define NG    2049                // scalar g samples, s = j/32 on [0,64]
#define NTAB2 2048                // float2 pair entries (16 KB)
#define INV_H 32.0f
#define CHUNKS 32
#define CLEN  64
#define WARM  128
#define BLOCK 256
#define SIM_GRID 1024             // 32 row-blocks * 32 chunks = 4 blocks/CU

#define WS_TAB 128                // scalar g table offset (floats) in d_ws

// --------------------------- setup: build LUT ------------------------------
__global__ __launch_bounds__(256) void setup_kernel(float* __restrict__ ws,
                                                    float* __restrict__ out) {
    __shared__ float  fx[NQ], fw[NQ];
    __shared__ double inv[NQ + 1];
    const int tid = threadIdx.x;
    if (tid <= NQ) inv[tid] = (tid == 0) ? 0.0 : 1.0 / (double)tid;
    __syncthreads();
    if (tid < NQ) {
        // Newton on P_64: guess err ~3e-4 -> 3 updates reach ~1e-15,
        // 4th pass evaluates pp at converged z (no update).
        double z = cos(3.14159265358979323846 * (tid + 0.75) / (NQ + 0.5));
        double p1 = 1.0, p2 = 0.0, pp = 1.0;
        for (int it = 0; it < 4; ++it) {
            p1 = 1.0; p2 = 0.0;
            for (int j = 1; j <= NQ; ++j) {
                double p3 = p2; p2 = p1;
                p1 = ((2.0 * j - 1.0) * z * p2 - (j - 1.0) * p3) * inv[j];
            }
            pp = NQ * (z * p1 - p2) / (z * z - 1.0);
            if (it < 3) z -= p1 / pp;
        }
        double w  = 2.0 / ((1.0 - z * z) * pp * pp);
        double xs = z * 5.0;                       // node scaled to [-5,5]
        fx[tid] = (float)xs;                       // f32 cast, like reference
        fw[tid] = (float)(w * 5.0 * exp(-0.5 * xs * xs) * 0.3989422804014327);
    }
    __syncthreads();
    const int j = blockIdx.x * BLOCK + tid;        // grid 32x256 = 8192
    if (j < NG) {                                  // g(s_j), s_j = j/32
        const float d = sqrtf((float)j * (1.0f / INV_H));
        float acc = 0.0f;
        #pragma unroll 8
        for (int q = 0; q < NQ; ++q) {
            float t = tanhf(d * fx[q]);
            acc = fmaf(fw[q], 1.0f - t * t, acc);
        }
        ws[WS_TAB + j] = acc;
    }
    out[(size_t)j * TP1] = 0.0f;                   // z_hist[:,0] = 0
}

// ------------------------------ main scan ----------------------------------
__device__ __forceinline__ float step_one(float uu, float& k1, float& k2,
                                          float& v, const float2* s_tab) {
    float s   = fmaf(k1, k1, fmaf(k2, k2, uu * uu));      // delta^2
    float idx = fminf(s * INV_H, 2046.999f);
    int   i0  = (int)idx;
    float f   = idx - (float)i0;
    float2 g2 = s_tab[i0];                                // one ds_read_b64
    float g   = fmaf(f, g2.y - g2.x, g2.x);               // gauss_int
    float gv  = g * v;
    float nk1 = fmaf(k1, fmaf(0.2f, g, 0.8f), 0.10f * gv);
    float nk2 = fmaf(k2, fmaf(0.1f, g, 0.8f), 0.38f * gv);
    v  = fmaf(0.2f, uu - v, v);
    k1 = nk1; k2 = nk2;
    return fmaf(2.8f, nk1, -2.2f * nk2);
}

__global__ __launch_bounds__(BLOCK, 4) void sim_kernel(const float* __restrict__ u,
                                                       const float* __restrict__ ws,
                                                       float* __restrict__ out) {
    __shared__ float2 s_tab[NTAB2];                // 16 KB pair table
    __shared__ float2 s_ub[2048];                  // 16 KB: 2 u-tiles of [4][256];
                                                   // aliased by 32x65 zt at flush
    const int tid = threadIdx.x;

    {   // pair-table fill from scalar g[] in ws (coalesced float4 + 1 scalar)
        const float* g = ws + WS_TAB;
        #pragma unroll
        for (int i = 0; i < NTAB2 / (BLOCK * 4); ++i) {   // 2 iters
            int k = (i * BLOCK + tid) * 4;
            float4 a = *(const float4*)(g + k);
            float  b = g[k + 4];
            s_tab[k + 0] = make_float2(a.x, a.y);
            s_tab[k + 1] = make_float2(a.y, a.z);
            s_tab[k + 2] = make_float2(a.z, a.w);
            s_tab[k + 3] = make_float2(a.w, b);
        }
    }   // first group's barrier orders these writes before any table read

    const int c    = blockIdx.x >> 5;              // chunk id (32)
    const int bb   = blockIdx.x & 31;              // row-block id (32)
    const int rowb = bb * BLOCK;
    const int t_out   = c * CLEN;                  // first owned step
    // clamp: chunks 0,1 start from the EXACT zero initial state at t=0
    const int t_begin = (t_out >= WARM) ? (t_out - WARM) : 0;

    float k1 = 0.f, k2 = 0.f, v = 0.f;
    const int r1 = tid >> 1;
    const int h4 = (tid & 1) * 4;
    const int ph = (tid & 1) * 2;
    const float* __restrict__ upb = u + (size_t)(rowb + r1) * Tlen + h4;

    float4 Ua = *(const float4*)(upb + t_begin);
    float4 Ub = *(const float4*)(upb + t_begin + 128 * Tlen);
    int gi = 0;                                    // group parity for dbuf

    // ---------------- warmup: state only, z discarded ----------------
    for (int tb = t_begin; tb < t_out; tb += 8, ++gi) {
        float2* ut = s_ub + (gi & 1) * 1024;       // this group's tile
        ut[ ph      * BLOCK + r1      ] = make_float2(Ua.x, Ua.y);
        ut[(ph + 1) * BLOCK + r1      ] = make_float2(Ua.z, Ua.w);
        ut[ ph      * BLOCK + r1 + 128] = make_float2(Ub.x, Ub.y);
        ut[(ph + 1) * BLOCK + r1 + 128] = make_float2(Ub.z, Ub.w);
        const int tn = tb + 8;                     // <= t_out <= 1984: in-bounds
        Ua = *(const float4*)(upb + tn);
        Ub = *(const float4*)(upb + tn + 128 * Tlen);
        __syncthreads();                           // tile ready (single barrier)
        #pragma unroll
        for (int p = 0; p < 4; ++p) {
            float2 uu = ut[p * BLOCK + tid];
            step_one(uu.x, k1, k2, v, s_tab);
            step_one(uu.y, k1, k2, v, s_tab);
        }
    }

    // ---------------- output: 64 steps, z kept in registers ----------------
    float zz[CLEN];
    #pragma unroll
    for (int gq = 0; gq < 8; ++gq, ++gi) {
        const int tb = t_out + gq * 8;
        float2* ut = s_ub + (gi & 1) * 1024;
        ut[ ph      * BLOCK + r1      ] = make_float2(Ua.x, Ua.y);
        ut[(ph + 1) * BLOCK + r1      ] = make_float2(Ua.z, Ua.w);
        ut[ ph      * BLOCK + r1 + 128] = make_float2(Ub.x, Ub.y);
        ut[(ph + 1) * BLOCK + r1 + 128] = make_float2(Ub.z, Ub.w);
        int tn = tb + 8;                           // clamp: last group of c=31
        if (tn > Tlen - 8) tn = Tlen - 8;
        Ua = *(const float4*)(upb + tn);
        Ub = *(const float4*)(upb + tn + 128 * Tlen);
        __syncthreads();
        #pragma unroll
        for (int p = 0; p < 4; ++p) {
            float2 uu = ut[p * BLOCK + tid];
            zz[gq * 8 + 2 * p    ] = step_one(uu.x, k1, k2, v, s_tab);
            zz[gq * 8 + 2 * p + 1] = step_one(uu.y, k1, k2, v, s_tab);
        }
    }

    // ---------------- terminal flush: 8 phases of 32 rows ----------------
    float* s_zt = (float*)s_ub;                    // 32*65 floats, aliases tiles
    const int cb = t_out + 1;                      // first output col
    const int lr = tid & 31;
    for (int p4 = 0; p4 < 8; ++p4) {
        __syncthreads();                           // zt free
        if ((tid >> 5) == p4) {                    // rows [32*p4, 32*p4+32)
            #pragma unroll
            for (int j = 0; j < 64; ++j)           // banks (lr+j)%32: free
                s_zt[lr * 65 + j] = zz[j];
        }
        __syncthreads();                           // zt ready
        #pragma unroll
        for (int k = 0; k < 8; ++k) {              // 32 rows x 64 cols
            int d   = tid + 256 * k;
            int row = d >> 6;
            int col = d & 63;
            out[(size_t)(rowb + p4 * 32 + row) * TP1 + cb + col] =
                s_zt[row * 65 + col];              // 256 B contiguous per wave
        }
    }
}

// ------------------------------ launcher -----------------------------------
extern "C" void kernel_launch(void* const* d_in, const int* in_sizes, int n_in,
                              void* d_out, int out_size, void* d_ws, size_t ws_size,
                              hipStream_t stream) {
    const float* u = (const float*)d_in[0];
    float* out = (float*)d_out;
    float* ws  = (float*)d_ws;                     // needs ~9 KB
    setup_kernel<<<32, BLOCK, 0, stream>>>(ws, out);
    sim_kernel<<<SIM_GRID, BLOCK, 0, stream>>>(u, ws, out);
}